// Round 2
// baseline (1043.280 us; speedup 1.0000x reference)
//
#include <hip/hip_runtime.h>
#include <math.h>

// Problem constants (B, N, D fixed by setup_inputs)
#define BB 32
#define NN 1024
#define DD 256
#define CH 8  // n-chunks for column-stats parallelism

// ---------------------------------------------------------------------------
// k_tw: tW = t @ W   where t is [BB*NN, DD] row-major, W is [DD, DD].
// 64x64 tile, 256 threads, 4x4 per thread, K-step 16, f32.
// ---------------------------------------------------------------------------
__global__ __launch_bounds__(256) void k_tw(const float* __restrict__ t,
                                            const float* __restrict__ W,
                                            float* __restrict__ tW) {
  const int row0 = blockIdx.x * 64;
  const int col0 = blockIdx.y * 64;
  __shared__ float As[16][68];  // [k][row]  (68 pad keeps 16B alignment, breaks conflicts)
  __shared__ float Bs[16][68];  // [k][col]
  const int tid = threadIdx.x;
  const int tx = tid & 15, ty = tid >> 4;
  float acc[4][4] = {};
  for (int k0 = 0; k0 < DD; k0 += 16) {
    #pragma unroll
    for (int it = 0; it < 4; ++it) {
      int e = tid + it * 256;
      int r = e >> 4, kk = e & 15;
      As[kk][r] = t[(size_t)(row0 + r) * DD + k0 + kk];
    }
    #pragma unroll
    for (int it = 0; it < 4; ++it) {
      int e = tid + it * 256;
      int kk = e >> 6, c = e & 63;
      Bs[kk][c] = W[(size_t)(k0 + kk) * DD + col0 + c];
    }
    __syncthreads();
    #pragma unroll
    for (int kk = 0; kk < 16; ++kk) {
      float4 av = *(const float4*)&As[kk][ty * 4];
      float4 bv = *(const float4*)&Bs[kk][tx * 4];
      float a[4] = {av.x, av.y, av.z, av.w};
      float b[4] = {bv.x, bv.y, bv.z, bv.w};
      #pragma unroll
      for (int i = 0; i < 4; ++i)
        #pragma unroll
        for (int j = 0; j < 4; ++j)
          acc[i][j] = fmaf(a[i], b[j], acc[i][j]);
    }
    __syncthreads();
  }
  #pragma unroll
  for (int i = 0; i < 4; ++i) {
    float4 v = {acc[i][0], acc[i][1], acc[i][2], acc[i][3]};
    *(float4*)&tW[(size_t)(row0 + ty * 4 + i) * DD + col0 + tx * 4] = v;
  }
}

// ---------------------------------------------------------------------------
// k_s: s[g][n][m] = tW[b][n][:] . f[b][m][:]   (NT GEMM per batch)
// ---------------------------------------------------------------------------
__global__ __launch_bounds__(256) void k_s(const float* __restrict__ tW,
                                           const float* __restrict__ f,
                                           float* __restrict__ s, int b0) {
  const int g = blockIdx.z;
  const int b = b0 + g;
  const int n0 = blockIdx.x * 64;
  const int m0 = blockIdx.y * 64;
  const float* A = tW + (size_t)b * NN * DD;
  const float* Bm = f + (size_t)b * NN * DD;
  float* S = s + (size_t)g * NN * NN;
  __shared__ float As[16][68];  // [k][n]
  __shared__ float Bs[16][68];  // [k][m]
  const int tid = threadIdx.x;
  const int tx = tid & 15, ty = tid >> 4;
  float acc[4][4] = {};
  for (int k0 = 0; k0 < DD; k0 += 16) {
    #pragma unroll
    for (int it = 0; it < 4; ++it) {
      int e = tid + it * 256;
      int r = e >> 4, kk = e & 15;
      As[kk][r] = A[(size_t)(n0 + r) * DD + k0 + kk];
      Bs[kk][r] = Bm[(size_t)(m0 + r) * DD + k0 + kk];
    }
    __syncthreads();
    #pragma unroll
    for (int kk = 0; kk < 16; ++kk) {
      float4 av = *(const float4*)&As[kk][ty * 4];
      float4 bv = *(const float4*)&Bs[kk][tx * 4];
      float a[4] = {av.x, av.y, av.z, av.w};
      float b2[4] = {bv.x, bv.y, bv.z, bv.w};
      #pragma unroll
      for (int i = 0; i < 4; ++i)
        #pragma unroll
        for (int j = 0; j < 4; ++j)
          acc[i][j] = fmaf(a[i], b2[j], acc[i][j]);
    }
    __syncthreads();
  }
  #pragma unroll
  for (int i = 0; i < 4; ++i) {
    float4 v = {acc[i][0], acc[i][1], acc[i][2], acc[i][3]};
    *(float4*)&S[(size_t)(n0 + ty * 4 + i) * NN + m0 + tx * 4] = v;
  }
}

// ---------------------------------------------------------------------------
// Row stats: rmax/rsum over axis=2 (per (b,n) row of s). One block per row.
// ---------------------------------------------------------------------------
__global__ __launch_bounds__(256) void k_rowstats(const float* __restrict__ s,
                                                  float* __restrict__ rmax,
                                                  float* __restrict__ rsum, int b0) {
  const int g = blockIdx.y;
  const int b = b0 + g;
  const int n = blockIdx.x;
  const float* row = s + (size_t)g * NN * NN + (size_t)n * NN;
  const int tid = threadIdx.x;
  float mx = -INFINITY, sum = 0.f;
  for (int j = tid; j < NN; j += 256) {
    float x = row[j];
    float nm = fmaxf(mx, x);
    sum = sum * __expf(mx - nm) + __expf(x - nm);
    mx = nm;
  }
  __shared__ float sm[256], ss[256];
  sm[tid] = mx; ss[tid] = sum;
  __syncthreads();
  for (int off = 128; off > 0; off >>= 1) {
    if (tid < off) {
      float m2 = sm[tid + off], s2 = ss[tid + off];
      float nm = fmaxf(sm[tid], m2);
      ss[tid] = ss[tid] * __expf(sm[tid] - nm) + s2 * __expf(m2 - nm);
      sm[tid] = nm;
    }
    __syncthreads();
  }
  if (tid == 0) {
    rmax[(size_t)b * NN + n] = sm[0];
    rsum[(size_t)b * NN + n] = ss[0];
  }
}

// ---------------------------------------------------------------------------
// Column stats (axis=1), chunked over n for parallelism, then combined.
// ---------------------------------------------------------------------------
__global__ __launch_bounds__(256) void k_colstats_part(const float* __restrict__ s,
                                                       float* __restrict__ pm,
                                                       float* __restrict__ ps) {
  const int g = blockIdx.z;
  const int ch = blockIdx.y;
  const int mcol = blockIdx.x * 256 + threadIdx.x;
  const float* S = s + (size_t)g * NN * NN;
  float mx = -INFINITY, sum = 0.f;
  const int n0 = ch * (NN / CH), n1 = n0 + NN / CH;
  for (int n = n0; n < n1; ++n) {
    float x = S[(size_t)n * NN + mcol];
    float nm = fmaxf(mx, x);
    sum = sum * __expf(mx - nm) + __expf(x - nm);
    mx = nm;
  }
  pm[((size_t)g * CH + ch) * NN + mcol] = mx;
  ps[((size_t)g * CH + ch) * NN + mcol] = sum;
}

__global__ __launch_bounds__(256) void k_colstats_comb(const float* __restrict__ pm,
                                                       const float* __restrict__ ps,
                                                       float* __restrict__ cmax,
                                                       float* __restrict__ csum, int b0) {
  const int g = blockIdx.y;
  const int b = b0 + g;
  const int mcol = blockIdx.x * 256 + threadIdx.x;
  float mx = -INFINITY, sum = 0.f;
  for (int ch = 0; ch < CH; ++ch) {
    float m2 = pm[((size_t)g * CH + ch) * NN + mcol];
    float s2 = ps[((size_t)g * CH + ch) * NN + mcol];
    float nm = fmaxf(mx, m2);
    sum = sum * __expf(mx - nm) + s2 * __expf(m2 - nm);
    mx = nm;
  }
  cmax[(size_t)b * NN + mcol] = mx;
  csum[(size_t)b * NN + mcol] = sum;
}

// ---------------------------------------------------------------------------
// k_out<MODE>: out[b][d][m] = sum_n A[b][n][d] * P[n][m]
//   MODE 0 (t_out): P[n][m] = exp(s[n][m]-cmax[m]) / csum[m]  (axis=1 softmax)
//   MODE 1 (f_out): P[n][m] = exp(s[n][m]-rmax[n]) / rsum[n]  (axis=2 softmax)
// ---------------------------------------------------------------------------
template <int MODE>
__global__ __launch_bounds__(256) void k_out(const float* __restrict__ Asrc,
                                             const float* __restrict__ s,
                                             const float* __restrict__ smax,
                                             const float* __restrict__ ssum,
                                             float* __restrict__ out, int b0) {
  const int g = blockIdx.z;
  const int b = b0 + g;
  const int m0 = blockIdx.x * 64;  // output column tile
  const int d0 = blockIdx.y * 64;  // output row tile
  const float* A = Asrc + (size_t)b * NN * DD;  // [n][d]
  const float* S = s + (size_t)g * NN * NN;     // [n][m]
  float* O = out + (size_t)b * DD * NN;         // [d][m]
  __shared__ float As[16][68];  // [k][d]
  __shared__ float Bs[16][68];  // [k][m]
  __shared__ float cm[64], cs[64];
  const int tid = threadIdx.x;
  const int tx = tid & 15, ty = tid >> 4;
  if (MODE == 0 && tid < 64) {
    cm[tid] = smax[(size_t)b * NN + m0 + tid];
    cs[tid] = 1.f / ssum[(size_t)b * NN + m0 + tid];
  }
  __syncthreads();
  float acc[4][4] = {};
  for (int k0 = 0; k0 < NN; k0 += 16) {
    #pragma unroll
    for (int it = 0; it < 4; ++it) {
      int e = tid + it * 256;
      int kk = e >> 6, c = e & 63;
      As[kk][c] = A[(size_t)(k0 + kk) * DD + d0 + c];
      float x = S[(size_t)(k0 + kk) * NN + m0 + c];
      float w;
      if (MODE == 0) {
        w = __expf(x - cm[c]) * cs[c];
      } else {
        float rm = smax[(size_t)b * NN + k0 + kk];
        float rs = ssum[(size_t)b * NN + k0 + kk];
        w = __expf(x - rm) / rs;
      }
      Bs[kk][c] = w;
    }
    __syncthreads();
    #pragma unroll
    for (int kk = 0; kk < 16; ++kk) {
      float4 av = *(const float4*)&As[kk][ty * 4];
      float4 bv = *(const float4*)&Bs[kk][tx * 4];
      float a[4] = {av.x, av.y, av.z, av.w};
      float b2[4] = {bv.x, bv.y, bv.z, bv.w};
      #pragma unroll
      for (int i = 0; i < 4; ++i)
        #pragma unroll
        for (int j = 0; j < 4; ++j)
          acc[i][j] = fmaf(a[i], b2[j], acc[i][j]);
    }
    __syncthreads();
  }
  #pragma unroll
  for (int i = 0; i < 4; ++i) {
    float4 v = {acc[i][0], acc[i][1], acc[i][2], acc[i][3]};
    *(float4*)&O[(size_t)(d0 + ty * 4 + i) * NN + m0 + tx * 4] = v;
  }
}

// ---------------------------------------------------------------------------
extern "C" void kernel_launch(void* const* d_in, const int* in_sizes, int n_in,
                              void* d_out, int out_size, void* d_ws, size_t ws_size,
                              hipStream_t stream) {
  const float* t = (const float*)d_in[0];
  const float* f = (const float*)d_in[1];
  const float* W = (const float*)d_in[2];
  float* out = (float*)d_out;

  // Workspace layout (floats):
  //   tW:   BB*NN*DD                     (32 MB)
  //   rmax, rsum, cmax, csum: BB*NN each (0.5 MB total)
  //   pcm, pcs: 32*CH*NN each            (2 MB total)
  //   sbuf: G*NN*NN                      (4 MB per batch in group)
  char* ws = (char*)d_ws;
  float* tW = (float*)ws;
  size_t off = (size_t)BB * NN * DD;
  float* rmax = tW + off;  off += (size_t)BB * NN;
  float* rsum = tW + off;  off += (size_t)BB * NN;
  float* cmax = tW + off;  off += (size_t)BB * NN;
  float* csum = tW + off;  off += (size_t)BB * NN;
  float* pcm  = tW + off;  off += (size_t)32 * CH * NN;
  float* pcs  = tW + off;  off += (size_t)32 * CH * NN;
  float* sbuf = tW + off;
  size_t fixed_bytes = off * sizeof(float);
  size_t per_batch = (size_t)NN * NN * sizeof(float);
  int G = 1;
  if (ws_size > fixed_bytes + per_batch) {
    size_t avail = (ws_size - fixed_bytes) / per_batch;
    G = (int)(avail < BB ? avail : BB);
    if (G < 1) G = 1;
  }

  float* out_t = out;                               // t_out [B,D,N]
  float* out_f = out + (size_t)BB * DD * NN;        // f_out [B,D,N]

  // Stage 1: tW = t @ W (all batches at once; t viewed as [BB*NN, DD])
  k_tw<<<dim3((BB * NN) / 64, DD / 64), 256, 0, stream>>>(t, W, tW);

  // Stage 2..5 per batch group
  for (int b0 = 0; b0 < BB; b0 += G) {
    int g = BB - b0 < G ? BB - b0 : G;
    k_s<<<dim3(NN / 64, NN / 64, g), 256, 0, stream>>>(tW, f, sbuf, b0);
    k_rowstats<<<dim3(NN, g), 256, 0, stream>>>(sbuf, rmax, rsum, b0);
    k_colstats_part<<<dim3(NN / 256, CH, g), 256, 0, stream>>>(sbuf, pcm, pcs);
    k_colstats_comb<<<dim3(NN / 256, g), 256, 0, stream>>>(pcm, pcs, cmax, csum, b0);
    k_out<0><<<dim3(NN / 64, DD / 64, g), 256, 0, stream>>>(t, sbuf, cmax, csum, out_t, b0);
    k_out<1><<<dim3(NN / 64, DD / 64, g), 256, 0, stream>>>(f, sbuf, rmax, rsum, out_f, b0);
  }
}

// Round 3
// 386.541 us; speedup vs baseline: 2.6990x; 2.6990x over previous
//
#include <hip/hip_runtime.h>
#include <math.h>

#define BB 32
#define NN 1024
#define DD 256
#define CH 8
#define KSTEP 32
#define LDK 40  // padded k-stride (shorts): 80B rows -> 2-way LDS aliasing (free), 16B aligned

typedef __attribute__((ext_vector_type(8))) short short8;
typedef __attribute__((ext_vector_type(8))) unsigned short u16x8;
typedef __attribute__((ext_vector_type(4))) float f32x4;

__device__ __forceinline__ unsigned short f2bf(float x) {
  unsigned u = __float_as_uint(x);
  unsigned r = (u + 0x7fffu + ((u >> 16) & 1u)) >> 16;
  return (unsigned short)r;
}
__device__ __forceinline__ float bf2f(unsigned short h) {
  return __uint_as_float((unsigned)h << 16);
}

// ---------------------------------------------------------------------------
// k_split: f32 -> bf16 hi/lo (elementwise), float4-vectorized.
// ---------------------------------------------------------------------------
__global__ __launch_bounds__(256) void k_split(const float* __restrict__ src,
                                               unsigned short* __restrict__ hi,
                                               unsigned short* __restrict__ lo, int n4) {
  int i = blockIdx.x * 256 + threadIdx.x;
  if (i >= n4) return;
  float4 v = ((const float4*)src)[i];
  float xs[4] = {v.x, v.y, v.z, v.w};
  ushort4 h4, l4;
  unsigned short* hp = (unsigned short*)&h4;
  unsigned short* lp = (unsigned short*)&l4;
  #pragma unroll
  for (int j = 0; j < 4; ++j) {
    unsigned short h = f2bf(xs[j]);
    hp[j] = h;
    lp[j] = f2bf(xs[j] - bf2f(h));
  }
  ((ushort4*)hi)[i] = h4;
  ((ushort4*)lo)[i] = l4;
}

// W [k][n] -> Wt [n][k], split into hi/lo.
__global__ __launch_bounds__(256) void k_splitW(const float* __restrict__ W,
                                                unsigned short* __restrict__ Wth,
                                                unsigned short* __restrict__ Wtl) {
  int k = blockIdx.x, n = threadIdx.x;
  float x = W[k * DD + n];
  unsigned short h = f2bf(x);
  Wth[n * DD + k] = h;
  Wtl[n * DD + k] = f2bf(x - bf2f(h));
}

// ---------------------------------------------------------------------------
// k_gemm_nt<EPI>: C = A @ B^T with split-bf16 A,B (hi*hi + hi*lo + lo*hi).
// A rows [*, 256], B rows [*, 256] (both k-consecutive). 128x128 tile, 4 waves.
//   EPI 0 (tW):  C split-stored to outh/outl (bf16 hi/lo), ldC=256, no batch.
//   EPI 1 (s):   C stored f32 to outf, ldC=NN, batched via blockIdx.z.
// ---------------------------------------------------------------------------
template <int EPI>
__global__ __launch_bounds__(256) void k_gemm_nt(const unsigned short* __restrict__ Ahg,
                                                 const unsigned short* __restrict__ Alg,
                                                 const unsigned short* __restrict__ Bhg,
                                                 const unsigned short* __restrict__ Blg,
                                                 unsigned short* __restrict__ outh,
                                                 unsigned short* __restrict__ outl,
                                                 float* __restrict__ outf, int b0) {
  size_t aoff = 0, boff = 0, coff = 0;
  int ldC = 256;
  if (EPI == 1) {
    int b = b0 + blockIdx.z;
    aoff = (size_t)b * NN * DD;
    boff = (size_t)b * NN * DD;
    coff = (size_t)blockIdx.z * NN * NN;
    ldC = NN;
  }
  const int n0 = blockIdx.x * 128, m0 = blockIdx.y * 128;
  __shared__ unsigned short Ah[128][LDK], Al[128][LDK], Bh[128][LDK], Bl[128][LDK];
  const int tid = threadIdx.x;
  const int lane = tid & 63, w = tid >> 6;
  const int wr = (w >> 1) * 64, wc = (w & 1) * 64;
  const int sr = tid >> 1, sk = (tid & 1) * 16;  // staging: row, k-offset

  f32x4 acc[4][4] = {};
  const int fr = lane & 15, fk = (lane >> 4) * 8;

  for (int k0 = 0; k0 < DD; k0 += KSTEP) {
    const size_t abase = aoff + (size_t)(n0 + sr) * DD + k0 + sk;
    const size_t bbase = boff + (size_t)(m0 + sr) * DD + k0 + sk;
    *(u16x8*)&Ah[sr][sk] = *(const u16x8*)&Ahg[abase];
    *(u16x8*)&Ah[sr][sk + 8] = *(const u16x8*)&Ahg[abase + 8];
    *(u16x8*)&Al[sr][sk] = *(const u16x8*)&Alg[abase];
    *(u16x8*)&Al[sr][sk + 8] = *(const u16x8*)&Alg[abase + 8];
    *(u16x8*)&Bh[sr][sk] = *(const u16x8*)&Bhg[bbase];
    *(u16x8*)&Bh[sr][sk + 8] = *(const u16x8*)&Bhg[bbase + 8];
    *(u16x8*)&Bl[sr][sk] = *(const u16x8*)&Blg[bbase];
    *(u16x8*)&Bl[sr][sk + 8] = *(const u16x8*)&Blg[bbase + 8];
    __syncthreads();
    short8 ah[4], al[4], bh[4], bl[4];
    #pragma unroll
    for (int mi = 0; mi < 4; ++mi) {
      ah[mi] = *(const short8*)&Ah[wr + mi * 16 + fr][fk];
      al[mi] = *(const short8*)&Al[wr + mi * 16 + fr][fk];
    }
    #pragma unroll
    for (int ni = 0; ni < 4; ++ni) {
      bh[ni] = *(const short8*)&Bh[wc + ni * 16 + fr][fk];
      bl[ni] = *(const short8*)&Bl[wc + ni * 16 + fr][fk];
    }
    #pragma unroll
    for (int mi = 0; mi < 4; ++mi)
      #pragma unroll
      for (int ni = 0; ni < 4; ++ni) {
        acc[mi][ni] = __builtin_amdgcn_mfma_f32_16x16x32_bf16(ah[mi], bh[ni], acc[mi][ni], 0, 0, 0);
        acc[mi][ni] = __builtin_amdgcn_mfma_f32_16x16x32_bf16(ah[mi], bl[ni], acc[mi][ni], 0, 0, 0);
        acc[mi][ni] = __builtin_amdgcn_mfma_f32_16x16x32_bf16(al[mi], bh[ni], acc[mi][ni], 0, 0, 0);
      }
    __syncthreads();
  }
  const int fq = (lane >> 4) * 4;
  #pragma unroll
  for (int mi = 0; mi < 4; ++mi)
    #pragma unroll
    for (int ni = 0; ni < 4; ++ni) {
      #pragma unroll
      for (int q = 0; q < 4; ++q) {
        int row = n0 + wr + mi * 16 + fq + q;
        int col = m0 + wc + ni * 16 + fr;
        float x = acc[mi][ni][q];
        if (EPI == 0) {
          unsigned short h = f2bf(x);
          outh[(size_t)row * 256 + col] = h;
          outl[(size_t)row * 256 + col] = f2bf(x - bf2f(h));
        } else {
          outf[coff + (size_t)row * ldC + col] = x;
        }
      }
    }
}

// ---------------------------------------------------------------------------
// Row stats -> lr = max + log(sumexp) over axis=2 (one block per (b,n) row).
// ---------------------------------------------------------------------------
__global__ __launch_bounds__(256) void k_rowstats(const float* __restrict__ s,
                                                  float* __restrict__ lr, int b0) {
  const int g = blockIdx.y, b = b0 + g, n = blockIdx.x;
  const float* row = s + (size_t)g * NN * NN + (size_t)n * NN;
  const int tid = threadIdx.x;
  float4 v = ((const float4*)row)[tid];
  float mx = fmaxf(fmaxf(v.x, v.y), fmaxf(v.z, v.w));
  float sum = __expf(v.x - mx) + __expf(v.y - mx) + __expf(v.z - mx) + __expf(v.w - mx);
  __shared__ float sm[256], ss[256];
  sm[tid] = mx; ss[tid] = sum;
  __syncthreads();
  for (int off = 128; off > 0; off >>= 1) {
    if (tid < off) {
      float m2 = sm[tid + off], s2 = ss[tid + off];
      float nm = fmaxf(sm[tid], m2);
      ss[tid] = ss[tid] * __expf(sm[tid] - nm) + s2 * __expf(m2 - nm);
      sm[tid] = nm;
    }
    __syncthreads();
  }
  if (tid == 0) lr[(size_t)b * NN + n] = sm[0] + __logf(ss[0]);
}

// ---------------------------------------------------------------------------
// Column stats (axis=1): chunked partials then combine -> lc = max + log(sum).
// ---------------------------------------------------------------------------
__global__ __launch_bounds__(256) void k_colstats_part(const float* __restrict__ s,
                                                       float* __restrict__ pm,
                                                       float* __restrict__ ps) {
  const int g = blockIdx.z, ch = blockIdx.y;
  const int mcol = blockIdx.x * 256 + threadIdx.x;
  const float* S = s + (size_t)g * NN * NN;
  float mx = -INFINITY, sum = 0.f;
  const int n0 = ch * (NN / CH), n1 = n0 + NN / CH;
  for (int n = n0; n < n1; ++n) {
    float x = S[(size_t)n * NN + mcol];
    float nm = fmaxf(mx, x);
    sum = sum * __expf(mx - nm) + __expf(x - nm);
    mx = nm;
  }
  pm[((size_t)g * CH + ch) * NN + mcol] = mx;
  ps[((size_t)g * CH + ch) * NN + mcol] = sum;
}

__global__ __launch_bounds__(256) void k_colstats_comb(const float* __restrict__ pm,
                                                       const float* __restrict__ ps,
                                                       float* __restrict__ lc, int b0) {
  const int g = blockIdx.y, b = b0 + g;
  const int mcol = blockIdx.x * 256 + threadIdx.x;
  float mx = -INFINITY, sum = 0.f;
  for (int ch = 0; ch < CH; ++ch) {
    float m2 = pm[((size_t)g * CH + ch) * NN + mcol];
    float s2 = ps[((size_t)g * CH + ch) * NN + mcol];
    float nm = fmaxf(mx, m2);
    sum = sum * __expf(mx - nm) + s2 * __expf(m2 - nm);
    mx = nm;
  }
  lc[(size_t)b * NN + mcol] = mx + __logf(sum);
}

// ---------------------------------------------------------------------------
// k_out_mfma<MODE>: out[d][col] = sum_k A[k][d] * exp(s[k][col] - L) (bf16 MFMA)
//   MODE 0 (t_out): A=t_hi, L = lc[col]   (softmax over k at fixed col)
//   MODE 1 (f_out): A=f_hi, L = lr[k]     (softmax over col at fixed k)
// Staging: per-column gather of 8 k-rows -> pack -> one ds_write_b128.
// ---------------------------------------------------------------------------
template <int MODE>
__global__ __launch_bounds__(256) void k_out_mfma(const unsigned short* __restrict__ Ahg,
                                                  const float* __restrict__ s,
                                                  const float* __restrict__ lse,
                                                  float* __restrict__ out, int b0) {
  const int g = blockIdx.z, b = b0 + g;
  const int m0 = blockIdx.x * 128;  // output cols
  const int d0 = blockIdx.y * 128;  // output rows (d)
  const unsigned short* A = Ahg + (size_t)b * NN * DD;
  const float* S = s + (size_t)g * NN * NN;
  float* O = out + (size_t)b * DD * NN;
  __shared__ unsigned short As_[128][LDK];  // [d][k]
  __shared__ unsigned short Bs_[128][LDK];  // [col][k]
  const int tid = threadIdx.x;
  const int lane = tid & 63, w = tid >> 6;
  const int wr = (w >> 1) * 64, wc = (w & 1) * 64;
  const int scol = tid & 127;
  const int kg0 = tid >> 7;  // 0..1
  float Lm = 0.f;
  if (MODE == 0) Lm = lse[(size_t)b * NN + m0 + scol];
  f32x4 acc[4][4] = {};
  const int fr = lane & 15, fk = (lane >> 4) * 8;

  for (int k0 = 0; k0 < NN; k0 += KSTEP) {
    #pragma unroll
    for (int ii = 0; ii < 2; ++ii) {
      const int kg = kg0 + ii * 2;  // 0..3
      const int kb = k0 + kg * 8;
      // B: P tile
      u16x8 pv;
      #pragma unroll
      for (int j = 0; j < 8; ++j) {
        float x = S[(size_t)(kb + j) * NN + m0 + scol];
        float L = (MODE == 0) ? Lm : lse[(size_t)b * NN + kb + j];
        pv[j] = f2bf(__expf(x - L));
      }
      *(u16x8*)&Bs_[scol][kg * 8] = pv;
      // A tile (transposed gather)
      u16x8 av;
      #pragma unroll
      for (int j = 0; j < 8; ++j) av[j] = A[(size_t)(kb + j) * DD + d0 + scol];
      *(u16x8*)&As_[scol][kg * 8] = av;
    }
    __syncthreads();
    short8 af[4], bf[4];
    #pragma unroll
    for (int mi = 0; mi < 4; ++mi) af[mi] = *(const short8*)&As_[wr + mi * 16 + fr][fk];
    #pragma unroll
    for (int ni = 0; ni < 4; ++ni) bf[ni] = *(const short8*)&Bs_[wc + ni * 16 + fr][fk];
    #pragma unroll
    for (int mi = 0; mi < 4; ++mi)
      #pragma unroll
      for (int ni = 0; ni < 4; ++ni)
        acc[mi][ni] = __builtin_amdgcn_mfma_f32_16x16x32_bf16(af[mi], bf[ni], acc[mi][ni], 0, 0, 0);
    __syncthreads();
  }
  const int fq = (lane >> 4) * 4;
  #pragma unroll
  for (int mi = 0; mi < 4; ++mi)
    #pragma unroll
    for (int ni = 0; ni < 4; ++ni)
      #pragma unroll
      for (int q = 0; q < 4; ++q) {
        int row = d0 + wr + mi * 16 + fq + q;
        int col = m0 + wc + ni * 16 + fr;
        O[(size_t)row * NN + col] = acc[mi][ni][q];
      }
}

// ---------------------------------------------------------------------------
extern "C" void kernel_launch(void* const* d_in, const int* in_sizes, int n_in,
                              void* d_out, int out_size, void* d_ws, size_t ws_size,
                              hipStream_t stream) {
  const float* t = (const float*)d_in[0];
  const float* f = (const float*)d_in[1];
  const float* W = (const float*)d_in[2];
  float* out = (float*)d_out;

  const size_t NE = (size_t)BB * NN * DD;  // 8.4M elems
  char* ws = (char*)d_ws;
  size_t off = 0;
  auto alloc = [&](size_t bytes) { char* p = ws + off; off += (bytes + 255) & ~(size_t)255; return p; };
  unsigned short* t_hi = (unsigned short*)alloc(NE * 2);
  unsigned short* t_lo = (unsigned short*)alloc(NE * 2);
  unsigned short* f_hi = (unsigned short*)alloc(NE * 2);
  unsigned short* f_lo = (unsigned short*)alloc(NE * 2);
  unsigned short* tw_hi = (unsigned short*)alloc(NE * 2);
  unsigned short* tw_lo = (unsigned short*)alloc(NE * 2);
  unsigned short* Wth = (unsigned short*)alloc((size_t)DD * DD * 2);
  unsigned short* Wtl = (unsigned short*)alloc((size_t)DD * DD * 2);
  float* lr = (float*)alloc((size_t)BB * NN * 4);
  float* lc = (float*)alloc((size_t)BB * NN * 4);
  float* pcm = (float*)alloc((size_t)32 * CH * NN * 4);
  float* pcs = (float*)alloc((size_t)32 * CH * NN * 4);
  size_t fixed_bytes = off;
  size_t per_batch = (size_t)NN * NN * sizeof(float);
  int G = 1;
  if (ws_size > fixed_bytes + per_batch) {
    size_t avail = (ws_size - fixed_bytes) / per_batch;
    G = (int)(avail < BB ? avail : BB);
    if (G < 1) G = 1;
  }
  float* sbuf = (float*)(ws + fixed_bytes);

  float* out_t = out;
  float* out_f = out + (size_t)BB * DD * NN;

  // Prologue: splits + tW
  k_split<<<(int)((NE / 4 + 255) / 256), 256, 0, stream>>>(t, t_hi, t_lo, (int)(NE / 4));
  k_split<<<(int)((NE / 4 + 255) / 256), 256, 0, stream>>>(f, f_hi, f_lo, (int)(NE / 4));
  k_splitW<<<DD, DD, 0, stream>>>(W, Wth, Wtl);
  k_gemm_nt<0><<<dim3(256, 2, 1), 256, 0, stream>>>(t_hi, t_lo, Wth, Wtl, tw_hi, tw_lo, nullptr, 0);

  for (int b0 = 0; b0 < BB; b0 += G) {
    int g = BB - b0 < G ? BB - b0 : G;
    k_gemm_nt<1><<<dim3(8, 8, g), 256, 0, stream>>>(tw_hi, tw_lo, f_hi, f_lo, nullptr, nullptr, sbuf, b0);
    k_rowstats<<<dim3(NN, g), 256, 0, stream>>>(sbuf, lr, b0);
    k_colstats_part<<<dim3(NN / 256, CH, g), 256, 0, stream>>>(sbuf, pcm, pcs);
    k_colstats_comb<<<dim3(NN / 256, g), 256, 0, stream>>>(pcm, pcs, lc, b0);
    k_out_mfma<0><<<dim3(8, 2, g), 256, 0, stream>>>(t_hi, sbuf, lc, out_t, b0);
    k_out_mfma<1><<<dim3(8, 2, g), 256, 0, stream>>>(f_hi, sbuf, lr, out_f, b0);
  }
}